// Round 14
// baseline (507.775 us; speedup 1.0000x reference)
//
#include <hip/hip_runtime.h>
#include <math.h>

// Problem constants
#define HH 128
#define WW 128
#define CC 128
#define KK 9
#define NPIX 16384           // H*W
#define NELEM 2097152        // NPIX*C
#define EPS 1e-5f

// LDS row stride for gather tiles, in halves. MUST keep row base 16B-aligned
// (mrow*LPAD*2 % 16 == 0) for ds_read_b128: LPAD=1164 (rounds 10-11) broke
// this -> misaligned/split b128 LDS reads -> deform 114->216us. The 5.9M
// SQ_LDS_BANK_CONFLICT at 1160 is the INHERENT serialization of 1024B-wide
// b128 reads -- not fixable. Keep 1160.
#define LPAD 1160
#define LPADD 580            // dwords

// Fixed weight-region layout (float offsets); image buffers laid out at
// runtime with NI = 5 (batched) or 1 (serial fallback) slots.
#define OFF_WCOMB 0          // [2][9][27][128] fp32      = 62208
#define OFF_BCOMB 62208      // [2][32] fp32              = 64
#define OFF_WB    62272      // fp16 B-frag deform w: 2*147456 ushort = 147456 floats
#define OFF_WC    209728     // fp16 B-frag conv w:   2*36864 ushort  = 36864 floats
#define OFF_APROJ 246592     // hi/lo bf16 A-frag proj w: 389120 ushort = 194560 floats
#define OFF_BUFS  441152     // image buffers start here

// Round 10/11 lessons: no XCD blockIdx swizzle (regressed badly); LPAD=1160.
// Round 13: deform is latency-bound (VALU 41 / Mfma 9 / Occ 40 / HBM 8.5%),
// occupancy LDS-capped at 2 blocks/CU; 64-px tiles would halve the B stream
// but drop to 1 block/CU and lose cross-block gather||MFMA overlap. Leave it.

typedef __bf16    bf16x8 __attribute__((ext_vector_type(8)));
typedef _Float16  f16x8  __attribute__((ext_vector_type(8)));
typedef _Float16  f16x2  __attribute__((ext_vector_type(2)));
typedef float     floatx4 __attribute__((ext_vector_type(4)));

__device__ __forceinline__ unsigned short f2bf(float f) {
    unsigned u = __float_as_uint(f);
    return (unsigned short)((u + 0x7FFF + ((u >> 16) & 1)) >> 16);   // RNE
}
__device__ __forceinline__ float bf2f(unsigned short h) {
    return __uint_as_float(((unsigned)h) << 16);
}
__device__ __forceinline__ unsigned short f2h(float f) {
    _Float16 h = (_Float16)f;                                        // v_cvt_f16_f32 (RNE)
    return __builtin_bit_cast(unsigned short, h);
}
__device__ __forceinline__ f16x2 h2bc(unsigned u) {
    return __builtin_bit_cast(f16x2, u);
}
// packed BN+ReLU: v_pk_fma_f16 + v_pk_max_f16
__device__ __forceinline__ f16x2 nrm2(f16x2 g, f16x2 sc, f16x2 sh) {
    f16x2 r = g * sc + sh;
    const f16x2 z = {(_Float16)0.f, (_Float16)0.f};
    return __builtin_elementwise_max(r, z);
}

// ---------------------------------------------------------------------------
// prep_xh: f32 -> raw f16 image for all images in ONE launch (round-5's
// failure was 10 serialized launches; batched this is +~10us streaming but
// removes conv0's 378 MB f32 scattered gather -> 189 MB f16, L2-friendlier).
// Values are f2h(raw f32): bit-identical to what conv0 used to produce.
// ---------------------------------------------------------------------------
__global__ __launch_bounds__(256) void prep_xh(
    const float* __restrict__ xi0, const float* __restrict__ xi1,
    const float* __restrict__ xi2, const float* __restrict__ xi3,
    const float* __restrict__ xi4, unsigned short* __restrict__ xhB)
{
    const int img = blockIdx.y;
    const float* xf = xi0;
    if (img == 1) xf = xi1; else if (img == 2) xf = xi2;
    else if (img == 3) xf = xi3; else if (img == 4) xf = xi4;
    const int g = blockIdx.x * 256 + threadIdx.x;   // 2048 blocks -> 524288
    const float4 v = ((const float4*)xf)[g];
    uint2 o;
    o.x = (unsigned)f2h(v.x) | ((unsigned)f2h(v.y) << 16);
    o.y = (unsigned)f2h(v.z) | ((unsigned)f2h(v.w) << 16);
    ((uint2*)xhB)[(size_t)img * 524288 + g] = o;
}

// ---------------------------------------------------------------------------
// setup1: all independent setup work in ONE launch:
//   blocks [0,704)    conv-compose layer 0 (wcomb/bcomb/wB swizzle)
//   blocks [704,1408) conv-compose layer 1
//   blocks [1408,2168) projA hi/lo bf16 A-fragment planes (760 blocks)
//   blocks [2168,2178) zero the STATS region (2560 floats)
// ---------------------------------------------------------------------------
__global__ __launch_bounds__(256) void setup1(
    const float* __restrict__ cw0, const float* __restrict__ cb0,
    const float* __restrict__ ow0, const float* __restrict__ mw0,
    const float* __restrict__ cw1, const float* __restrict__ cb1,
    const float* __restrict__ ow1, const float* __restrict__ mw1,
    const float* __restrict__ s0, const float* __restrict__ s1,
    const float* __restrict__ s2, const float* __restrict__ s3,
    const float* __restrict__ s4, const float* __restrict__ s5,
    const float* __restrict__ s6, const float* __restrict__ s7,
    float* __restrict__ wcombB, float* __restrict__ bcombB,
    unsigned short* __restrict__ wBB, unsigned short* __restrict__ aP,
    float* __restrict__ stats)
{
    const int b = blockIdx.x;
    if (b < 1408) {
        const int layer = (b >= 704);
        const float* cw = layer ? cw1 : cw0;
        const float* cb = layer ? cb1 : cb0;
        const float* ow = layer ? ow1 : ow0;
        const float* mw = layer ? mw1 : mw0;
        float* wcomb = wcombB + layer * 31104;
        float* bcomb = bcombB + layer * 32;
        unsigned short* wBu = wBB + layer * 147456;
        int tid = (b - layer * 704) * 256 + threadIdx.x;
        if (tid < 31104) {
            int c = tid & 127;
            int o = (tid >> 7) % 27;
            int k = tid / 3456;                  // k in [0,9)
            const float* sel = (o < 18) ? (ow + o * 128) : (mw + (o - 18) * 128);
            float v = 0.f;
            for (int cp = 0; cp < 128; ++cp)
                v = fmaf(sel[cp], cw[cp * 1152 + c * 9 + k], v);
            wcomb[tid] = v;                      // wcomb[k][o][c]
        } else if (tid < 31104 + 27) {
            int o = tid - 31104;
            const float* sel = (o < 18) ? (ow + o * 128) : (mw + (o - 18) * 128);
            float v = 0.f;
            for (int cp = 0; cp < 128; ++cp)
                v = fmaf(sel[cp], cb[cp], v);
            bcomb[o] = v;
        } else if (tid >= 32768 && tid < 32768 + 147456) {
            int i = tid - 32768;
            int j    = i & 7;
            int lane = (i >> 3) & 63;
            int t    = (i >> 9) & 7;
            int s    = i >> 12;                  // 0..35
            int kc   = s * 32 + ((lane >> 4) << 3) + j;
            int o    = t * 16 + (lane & 15);
            wBu[i] = f2h(cw[o * 1152 + (kc & 127) * 9 + (kc >> 7)]);
        }
    } else if (b < 2168) {
        const int Os[8]   = {20, 80, 150, 150, 210, 210, 308, 308};
        const int nOt[8]  = {2, 5, 10, 10, 14, 14, 20, 20};
        const int tOff[8] = {0, 4096, 14336, 34816, 55296, 83968, 112640, 153600};
        const int dOff[8] = {0, 8192, 28672, 69632, 110592, 167936, 225280, 307200};
        int tid = (b - 1408) * 256 + threadIdx.x;     // < 194560
        int m = 0;
        #pragma unroll
        for (int q = 1; q < 8; ++q) if (tid >= tOff[q]) m = q;
        const float* src;
        switch (m) {
            case 0: src = s0; break; case 1: src = s1; break;
            case 2: src = s2; break; case 3: src = s3; break;
            case 4: src = s4; break; case 5: src = s5; break;
            case 6: src = s6; break; default: src = s7; break;
        }
        int i = tid - tOff[m];
        int j    = i & 7;
        int lane = (i >> 3) & 63;
        int s    = (i >> 9) & 3;
        int ot   = i >> 11;
        int o = ot * 16 + (lane & 15);
        int c = s * 32 + ((lane >> 4) << 3) + j;
        float v = (o < Os[m]) ? src[o * 128 + c] : 0.f;
        unsigned short h = f2bf(v);
        unsigned short l = f2bf(v - bf2f(h));
        const int hiSize = nOt[m] * 2048;
        aP[dOff[m] + i] = h;
        aP[dOff[m] + hiSize + i] = l;
    } else {
        const int i = (b - 2168) * 256 + threadIdx.x;
        if (i < 2560) stats[i] = 0.f;
    }
}

// ---------------------------------------------------------------------------
// setup2: both layers' composed-conv-weight B-fragment swizzles (reads wcomb
// produced by setup1, so it must be a separate dispatch).
// ---------------------------------------------------------------------------
__global__ __launch_bounds__(256) void setup2(
    const float* __restrict__ wcombB, unsigned short* __restrict__ wCB)
{
    const int b = blockIdx.x;
    const int layer = (b >= 144);
    const float* wcomb = wcombB + layer * 31104;
    unsigned short* wC = wCB + layer * 36864;
    int i = (b - layer * 144) * 256 + threadIdx.x;
    if (i >= 36864) return;
    int j    = i & 7;
    int lane = (i >> 3) & 63;
    int grp  = i >> 9;                       // s*2 + t
    int t = grp & 1, s = grp >> 1;
    int kc = s * 32 + ((lane >> 4) << 3) + j;
    int o  = t * 16 + (lane & 15);
    int c = kc & 127, k = kc >> 7;
    float v = (o < 27) ? wcomb[k * 3456 + o * 128 + c] : 0.f;
    wC[i] = f2h(v);
}

// ---------------------------------------------------------------------------
// conv_offm, 512 threads (8 waves), 16 px/block, blockIdx.y = image.
// Gather always reads a raw f16 image (xhB): blk0 from prep_xh's XH
// (NORM=false, pure copy); blk1 from deform0's YH with packed BN+ReLU
// (NORM=true). MFMA: wave = (t = wid&1, kq = wid>>1), 9 K-steps with B
// prefetch; 4-way K-reduction through recycled LDS. Epilogue emits packed
// gather descriptors.
// ---------------------------------------------------------------------------
template <bool NORM>
__global__ __launch_bounds__(512, 8) void conv_offm(
    const unsigned short* __restrict__ xhB,
    const unsigned short* __restrict__ wC, const float* __restrict__ bcomb,
    const float* __restrict__ stB, const float* __restrict__ bg,
    const float* __restrict__ bb,
    unsigned* __restrict__ offaB, float* __restrict__ offwB)
{
    __shared__ unsigned short smp[16 * LPAD];   // 37120 B -> 4 blocks/CU
    float* red  = (float*)smp;                  // recycled: [3][2][16][16] = 1536 f
    float* vals = red + 1536;                   // recycled: [16][33]       = 528 f
    float* maskL = red;                         // recycled again: [16][9]

    const int img  = blockIdx.y;
    const int gp0  = blockIdx.x * 16;
    const int lane = threadIdx.x & 63;
    const int wid  = threadIdx.x >> 6;          // 0..7
    const int half = lane >> 5;
    const int cl   = lane & 31;                 // channel-quad index

    const uint2* x2 = (const uint2*)xhB + (size_t)img * 524288;
    uint2*  offa2 = (uint2*)offaB + (size_t)img * 147456;
    float4* offw4 = (float4*)offwB + (size_t)img * 147456;

    f16x2 scp0, scp1, shp0, shp1;
    if constexpr (NORM) {
        const float* st = stB + (size_t)img * 512;
        float sc4[4], sh4[4];
        #pragma unroll
        for (int j = 0; j < 4; ++j) {
            const int c = cl * 4 + j;
            const float mean = st[c] * (1.f / 16384.f);
            const float var  = st[128 + c] * (1.f / 16384.f) - mean * mean;
            const float rstd = rsqrtf(var + EPS);
            sc4[j] = bg[c] * rstd;
            sh4[j] = bb[c] - mean * sc4[j];
        }
        scp0 = (f16x2){(_Float16)sc4[0], (_Float16)sc4[1]};
        scp1 = (f16x2){(_Float16)sc4[2], (_Float16)sc4[3]};
        shp0 = (f16x2){(_Float16)sh4[0], (_Float16)sh4[1]};
        shp1 = (f16x2){(_Float16)sh4[2], (_Float16)sh4[3]};
    }

    // ---- gather: wave wid handles pixels 2*wid + half ----
    {
        const int pl = wid * 2 + half;
        const int gp = gp0 + pl;
        const int h0 = gp >> 7, w0 = gp & 127;
        unsigned* dstq = (unsigned*)smp + pl * LPADD + cl * 2;
        #pragma unroll
        for (int k = 0; k < 9; ++k) {
            const int ny = h0 + k / 3 - 1;
            const int nx = w0 + k % 3 - 1;
            const int cy = min(max(ny, 0), 127);
            const int cx = min(max(nx, 0), 127);
            const bool ok = ((unsigned)ny < 128u) & ((unsigned)nx < 128u);
            const uint2 g = x2[(((cy << 7) + cx) << 5) + cl];
            unsigned d0, d1;
            if constexpr (NORM) {
                const f16x2 pa = nrm2(h2bc(g.x), scp0, shp0);
                const f16x2 pb = nrm2(h2bc(g.y), scp1, shp1);
                d0 = __builtin_bit_cast(unsigned, pa);
                d1 = __builtin_bit_cast(unsigned, pb);
            } else {
                d0 = g.x;
                d1 = g.y;
            }
            d0 = ok ? d0 : 0u;
            d1 = ok ? d1 : 0u;
            *(uint2*)(dstq + k * 64) = make_uint2(d0, d1);
        }
    }
    __syncthreads();

    // ---- MFMA: wave = (t = wid&1, kq = wid>>1), 9 K-steps each ----
    const int t    = wid & 1;
    const int kq   = wid >> 1;
    const int mrow = lane & 15;
    const int quad = lane >> 4;
    floatx4 acc = {0.f, 0.f, 0.f, 0.f};
    const unsigned short* arow = smp + mrow * LPAD + quad * 8;
    const unsigned short* bbase = wC + t * 512 + (lane << 3);
    f16x8 b = *(const f16x8*)(bbase + (kq * 9) * 1024);
    #pragma unroll
    for (int j = 0; j < 9; ++j) {
        const int s = kq * 9 + j;
        f16x8 nb;
        if (j < 8) nb = *(const f16x8*)(bbase + (s + 1) * 1024);
        const f16x8 a = *(const f16x8*)(arow + s * 32);
        acc = __builtin_amdgcn_mfma_f32_16x16x32_f16(a, b, acc, 0, 0, 0);
        if (j < 8) b = nb;
    }
    __syncthreads();   // all smp reads done; safe to recycle as red/vals

    // D: row (pixel) = quad*4+r, col (channel) = lane&15
    if (kq > 0) {
        #pragma unroll
        for (int r = 0; r < 4; ++r)
            red[(((kq - 1) * 2 + t) << 8) + (quad * 4 + r) * 16 + mrow] = acc[r];
    }
    __syncthreads();
    if (kq == 0) {
        #pragma unroll
        for (int r = 0; r < 4; ++r) {
            const int rc = (quad * 4 + r) * 16 + mrow;
            const float sv = acc[r] + red[(t << 8) + rc]
                           + red[((2 + t) << 8) + rc] + red[((4 + t) << 8) + rc];
            vals[(quad * 4 + r) * 33 + t * 16 + mrow] = sv;
        }
    }
    __syncthreads();

    // ---- epilogue A: lanes < 16 compute softmax masks into maskL ----
    if (threadIdx.x < 16) {
        const int p = threadIdx.x;
        const float* vp = vals + p * 33;
        float e[9], se = 0.f, mx = -1e30f;
        #pragma unroll
        for (int k = 0; k < 9; ++k) {
            e[k] = vp[18 + k] + bcomb[18 + k];
            mx = fmaxf(mx, e[k]);
        }
        #pragma unroll
        for (int k = 0; k < 9; ++k) { e[k] = expf(e[k] - mx); se += e[k]; }
        const float inv = 1.f / se;
        #pragma unroll
        for (int k = 0; k < 9; ++k) maskL[p * 9 + k] = e[k] * inv;
    }
    __syncthreads();

    // ---- epilogue B: 144 threads emit packed gather descriptors ----
    if (threadIdx.x < 144) {
        const int p = threadIdx.x / 9;
        const int k = threadIdx.x - p * 9;
        const int gp = gp0 + p;
        const int hh = gp >> 7, ww = gp & 127;
        const float* vp = vals + p * 33;
        const float py = (float)(hh - 1 + k / 3) + vp[2 * k]     + bcomb[2 * k];
        const float px = (float)(ww - 1 + k % 3) + vp[2 * k + 1] + bcomb[2 * k + 1];
        const float mk = maskL[p * 9 + k];
        const float y0f = floorf(py), x0f = floorf(px);
        const int iy0 = (int)y0f, ix0 = (int)x0f;
        const float wy1 = py - y0f, wy0 = 1.f - wy1;
        const float wx1 = px - x0f, wx0 = 1.f - wx1;
        const int cy0 = min(max(iy0, 0), 127);
        const int cy1 = min(max(iy0 + 1, 0), 127);
        const int cx0 = min(max(ix0, 0), 127);
        const int cx1 = min(max(ix0 + 1, 0), 127);
        const float vy0 = ((unsigned)iy0       < 128u) ? 1.f : 0.f;
        const float vy1 = ((unsigned)(iy0 + 1) < 128u) ? 1.f : 0.f;
        const float vx0 = ((unsigned)ix0       < 128u) ? 1.f : 0.f;
        const float vx1 = ((unsigned)(ix0 + 1) < 128u) ? 1.f : 0.f;
        const float w00 = wy0 * wx0 * vy0 * vx0 * mk;
        const float w01 = wy0 * wx1 * vy0 * vx1 * mk;
        const float w10 = wy1 * wx0 * vy1 * vx0 * mk;
        const float w11 = wy1 * wx1 * vy1 * vx1 * mk;
        const unsigned i00 = (unsigned)((cy0 << 7) | cx0);
        const unsigned i01 = (unsigned)((cy0 << 7) | cx1);
        const unsigned i10 = (unsigned)((cy1 << 7) | cx0);
        const unsigned i11 = (unsigned)((cy1 << 7) | cx1);
        offa2[(size_t)gp * 9 + k] =
            make_uint2(i00 | (i01 << 16), i10 | (i11 << 16));
        offw4[(size_t)gp * 9 + k] = make_float4(w00, w01, w10, w11);
    }
}

// ---------------------------------------------------------------------------
// deform, 512 threads (8 waves), 32 px/block, blockIdx.y = image. Gather:
// all 9 descriptor pairs preloaded into registers per pass (r12: breaks the
// per-tap desc->corner serial chain). Corners from the f16 image.
// NORM=false (blk0): no norm, f16 output yh + stats at img*512. NORM=true
// (blk1): packed-f16 BN+ReLU per corner; f32 output, stats at img*512+256.
// MFMA: wave wid owns N-tile wid over M=32 px as 2 M-subtiles; 6-deep B
// prefetch. Epilogue: store + fused sum/sumsq stats.
// ---------------------------------------------------------------------------
template <bool NORM>
__global__ __launch_bounds__(512, 4) void deform_kernel(
    const unsigned short* __restrict__ xhB,
    const unsigned* __restrict__ offaB, const float* __restrict__ offwB,
    const unsigned short* __restrict__ wBu, const float* __restrict__ cb,
    float* __restrict__ stB, const float* __restrict__ bg,
    const float* __restrict__ bb,
    float* __restrict__ yB, unsigned short* __restrict__ yhB)
{
    __shared__ unsigned short smp[32 * LPAD];   // 74240 B -> 2 blocks/CU

    const int img  = blockIdx.y;
    const int gp0  = blockIdx.x * 32;
    const int lane = threadIdx.x & 63;
    const int wid  = threadIdx.x >> 6;          // 0..7
    const int half = lane >> 5;
    const int cl   = lane & 31;
    const uint2* x2 = (const uint2*)xhB + (size_t)img * 524288;
    const uint2*  apB = (const uint2*)offaB + (size_t)img * 147456;
    const float4* wpB = (const float4*)offwB + (size_t)img * 147456;

    f16x2 scp0, scp1, shp0, shp1;
    if constexpr (NORM) {
        const float* stp = stB + (size_t)img * 512;
        float sc4[4], sh4[4];
        #pragma unroll
        for (int j = 0; j < 4; ++j) {
            const int c = cl * 4 + j;
            const float mean = stp[c] * (1.f / 16384.f);
            const float var  = stp[128 + c] * (1.f / 16384.f) - mean * mean;
            const float rstd = rsqrtf(var + EPS);
            sc4[j] = bg[c] * rstd;
            sh4[j] = bb[c] - mean * sc4[j];
        }
        scp0 = (f16x2){(_Float16)sc4[0], (_Float16)sc4[1]};
        scp1 = (f16x2){(_Float16)sc4[2], (_Float16)sc4[3]};
        shp0 = (f16x2){(_Float16)sh4[0], (_Float16)sh4[1]};
        shp1 = (f16x2){(_Float16)sh4[2], (_Float16)sh4[3]};
    }

    // ---- phase 1: wave wid gathers pixels wid*4 + pass*2 + half ----
    for (int pass = 0; pass < 2; ++pass) {
        const int pl = wid * 4 + pass * 2 + half;
        const size_t tb = (size_t)(gp0 + pl) * 9;
        const uint2*  ap = apB + tb;
        const float4* wp = wpB + tb;
        unsigned* dstq = (unsigned*)smp + pl * LPADD + cl * 2;
        // preload all descriptors (issues 18 loads back-to-back)
        uint2  aq[9];
        float4 wq[9];
        #pragma unroll
        for (int k = 0; k < 9; ++k) { aq[k] = ap[k]; wq[k] = wp[k]; }
        #pragma unroll
        for (int k = 0; k < 9; ++k) {
            const uint2  a = aq[k];
            const float4 w = wq[k];
            const int i00 = (int)(a.x & 0xFFFFu) << 5;
            const int i01 = (int)(a.x >> 16) << 5;
            const int i10 = (int)(a.y & 0xFFFFu) << 5;
            const int i11 = (int)(a.y >> 16) << 5;
            const uint2 G00 = x2[i00 + cl];
            const uint2 G01 = x2[i01 + cl];
            const uint2 G10 = x2[i10 + cl];
            const uint2 G11 = x2[i11 + cl];
            f16x2 a00 = h2bc(G00.x), b00 = h2bc(G00.y);
            f16x2 a01 = h2bc(G01.x), b01 = h2bc(G01.y);
            f16x2 a10 = h2bc(G10.x), b10 = h2bc(G10.y);
            f16x2 a11 = h2bc(G11.x), b11 = h2bc(G11.y);
            if constexpr (NORM) {
                a00 = nrm2(a00, scp0, shp0); b00 = nrm2(b00, scp1, shp1);
                a01 = nrm2(a01, scp0, shp0); b01 = nrm2(b01, scp1, shp1);
                a10 = nrm2(a10, scp0, shp0); b10 = nrm2(b10, scp1, shp1);
                a11 = nrm2(a11, scp0, shp0); b11 = nrm2(b11, scp1, shp1);
            }
            // f32 accumulation directly from packed halves (fma_mix)
            const float s0 = fmaf(w.x, (float)a00.x, fmaf(w.y, (float)a01.x,
                             fmaf(w.z, (float)a10.x, w.w * (float)a11.x)));
            const float s1 = fmaf(w.x, (float)a00.y, fmaf(w.y, (float)a01.y,
                             fmaf(w.z, (float)a10.y, w.w * (float)a11.y)));
            const float s2 = fmaf(w.x, (float)b00.x, fmaf(w.y, (float)b01.x,
                             fmaf(w.z, (float)b10.x, w.w * (float)b11.x)));
            const float s3 = fmaf(w.x, (float)b00.y, fmaf(w.y, (float)b01.y,
                             fmaf(w.z, (float)b10.y, w.w * (float)b11.y)));
            const unsigned d0 = (unsigned)f2h(s0) | ((unsigned)f2h(s1) << 16);
            const unsigned d1 = (unsigned)f2h(s2) | ((unsigned)f2h(s3) << 16);
            *(uint2*)(dstq + k * 64) = make_uint2(d0, d1);
        }
    }
    __syncthreads();

    // ---- phase 2: wave wid owns N-tile wid, M = 2 subtiles, K = 36 ----
    const int mrow = lane & 15;
    const int quad = lane >> 4;
    const unsigned short* arow0 = smp + mrow * LPAD + quad * 8;
    const unsigned short* arow1 = arow0 + 16 * LPAD;
    const unsigned short* bbase = wBu + wid * 512 + (lane << 3);
    floatx4 acc0 = {0.f, 0.f, 0.f, 0.f};
    floatx4 acc1 = {0.f, 0.f, 0.f, 0.f};
    f16x8 bq0 = *(const f16x8*)(bbase);
    f16x8 bq1 = *(const f16x8*)(bbase + 4096);
    f16x8 bq2 = *(const f16x8*)(bbase + 2 * 4096);
    f16x8 bq3 = *(const f16x8*)(bbase + 3 * 4096);
    f16x8 bq4 = *(const f16x8*)(bbase + 4 * 4096);
    f16x8 bq5 = *(const f16x8*)(bbase + 5 * 4096);
    #pragma unroll
    for (int s = 0; s < 36; ++s) {
        f16x8 nb;
        if (s < 30) nb = *(const f16x8*)(bbase + (size_t)(s + 6) * 4096);
        const f16x8 a0 = *(const f16x8*)(arow0 + s * 32);
        const f16x8 a1 = *(const f16x8*)(arow1 + s * 32);
        acc0 = __builtin_amdgcn_mfma_f32_16x16x32_f16(a0, bq0, acc0, 0, 0, 0);
        acc1 = __builtin_amdgcn_mfma_f32_16x16x32_f16(a1, bq0, acc1, 0, 0, 0);
        bq0 = bq1; bq1 = bq2; bq2 = bq3; bq3 = bq4; bq4 = bq5;
        if (s < 30) bq5 = nb;
    }

    // ---- epilogue: store + per-channel stats (channel n = wid*16+mrow) ----
    const int n = wid * 16 + mrow;
    const float bias = cb[n];
    float ssum = 0.f, qsum = 0.f;
    #pragma unroll
    for (int r = 0; r < 4; ++r) {
        const float v0 = acc0[r] + bias;
        const float v1 = acc1[r] + bias;
        if constexpr (!NORM) {
            unsigned short* yh = yhB + (size_t)img * 2097152;
            yh[(size_t)(gp0 + quad * 4 + r) * 128 + n]      = f2h(v0);
            yh[(size_t)(gp0 + 16 + quad * 4 + r) * 128 + n] = f2h(v1);
        } else {
            float* y = yB + (size_t)img * 2097152;
            y[(size_t)(gp0 + quad * 4 + r) * 128 + n]      = v0;
            y[(size_t)(gp0 + 16 + quad * 4 + r) * 128 + n] = v1;
        }
        ssum += v0 + v1;
        qsum = fmaf(v0, v0, qsum);
        qsum = fmaf(v1, v1, qsum);
    }
    ssum += __shfl_xor(ssum, 16); qsum += __shfl_xor(qsum, 16);
    ssum += __shfl_xor(ssum, 32); qsum += __shfl_xor(qsum, 32);
    if (quad == 0) {
        float* stw = stB + (size_t)img * 512 + (NORM ? 256 : 0);
        atomicAdd(&stw[n], ssum);
        atomicAdd(&stw[128 + n], qsum);
    }
}

// ---------------------------------------------------------------------------
// proj_all: ALL 5 images' 1x1 projections + fused final LN in ONE dispatch.
// blockIdx.y in [0,15) maps to (img, ot-group) via lookup. DUAL (second
// GEMM from the raw input) is a block-uniform runtime branch for img>=2.
// ---------------------------------------------------------------------------
__global__ __launch_bounds__(256) void proj_all(
    const float* __restrict__ bufB,
    const float* __restrict__ xi0, const float* __restrict__ xi1,
    const float* __restrict__ xi2, const float* __restrict__ xi3,
    const float* __restrict__ xi4,
    const unsigned short* __restrict__ aP,
    const float* __restrict__ stats, const float* __restrict__ bgn,
    const float* __restrict__ bbn,
    const float* __restrict__ lnw, const float* __restrict__ lnb,
    float* __restrict__ out)
{
    const int yImg[15]  = {0,1,1,2,2,2,3,3,3,3,4,4,4,4,4};
    const int yOtg[15]  = {0,0,1,0,1,2,0,1,2,3,0,1,2,3,4};
    const int OcntT[5]  = {20, 80, 150, 210, 308};
    const int ObaseT[5] = {0, 20, 100, 250, 460};
    const int aOffAT[5] = {0, 8192, 28672, 110592, 225280};
    const int aOffBT[5] = {0, 0, 69632, 167936, 307200};
    const int hiSzT[5]  = {4096, 10240, 20480, 28672, 40960};

    const int ylin = blockIdx.y;
    const int img  = yImg[ylin];
    const int otg  = yOtg[ylin];
    const bool dual = (img >= 2);
    const int O = OcntT[img];
    const int hiSize = hiSzT[img];
    const float* xc = bufB + (size_t)img * 2097152;
    const float* xp = xi0;
    if (img == 1) xp = xi1; else if (img == 2) xp = xi2;
    else if (img == 3) xp = xi3; else if (img == 4) xp = xi4;
    const unsigned short* aPA = aP + aOffAT[img];
    const unsigned short* aPB = aP + aOffBT[img];
    const float* stn = stats + (size_t)img * 512 + 256;
    float* outI = out + (size_t)ObaseT[img] * NPIX;

    __shared__ unsigned short sm[4 * 64 * 136];
    unsigned short* shA = sm;
    unsigned short* slA = sm + 64 * 136;
    const int row0 = blockIdx.x * 128;          // one full h-row

    const int lane = threadIdx.x & 63;
    const int wid  = threadIdx.x >> 6;
    const int quad = lane >> 4;
    const int nrow = lane & 15;
    const int nOt  = (O + 15) >> 4;
    const int ot   = otg * 4 + wid;

    bf16x8 AhA[4], AlA[4], AhB[4], AlB[4];
    if (ot < nOt) {
        #pragma unroll
        for (int s = 0; s < 4; ++s) {
            const int idx = ((ot * 4 + s) * 64 + lane) * 8;
            AhA[s] = *(const bf16x8*)(aPA + idx);
            AlA[s] = *(const bf16x8*)(aPA + hiSize + idx);
            if (dual) {
                AhB[s] = *(const bf16x8*)(aPB + idx);
                AlB[s] = *(const bf16x8*)(aPB + hiSize + idx);
            }
        }
    }

    floatx4 acc[8];
    #pragma unroll
    for (int i = 0; i < 8; ++i) acc[i] = (floatx4){0.f, 0.f, 0.f, 0.f};

    #pragma unroll
    for (int hlf = 0; hlf < 2; ++hlf) {
        if (hlf) __syncthreads();               // prev GEMM reads done
        const int gp0 = row0 + hlf * 64;
        for (int i = threadIdx.x; i < 4096; i += 256) {
            const int p = i >> 6, c2 = (i & 63) * 2;
            float2 v = *(const float2*)(xc + (size_t)(gp0 + p) * 128 + c2);
            #pragma unroll
            for (int j = 0; j < 2; ++j) {
                const int c = c2 + j;
                const float mean = stn[c] * (1.f / 16384.f);
                const float var  = stn[128 + c] * (1.f / 16384.f) - mean * mean;
                const float rstd = rsqrtf(var + EPS);
                const float scn = bgn[c] * rstd;
                const float shn = bbn[c] - mean * scn;
                float vv = j ? v.y : v.x;
                vv = fmaxf(fmaf(vv, scn, shn), 0.f);
                if (j) v.y = vv; else v.x = vv;
            }
            {
                const unsigned short h0 = f2bf(v.x), h1 = f2bf(v.y);
                const unsigned short l0 = f2bf(v.x - bf2f(h0)), l1 = f2bf(v.y - bf2f(h1));
                ((unsigned*)shA)[p * 68 + (c2 >> 1)] = (unsigned)h0 | ((unsigned)h1 << 16);
                ((unsigned*)slA)[p * 68 + (c2 >> 1)] = (unsigned)l0 | ((unsigned)l1 << 16);
            }
            if (dual) {
                unsigned short* shB = sm + 2 * 64 * 136;
                unsigned short* slB = sm + 3 * 64 * 136;
                const float2 u = *(const float2*)(xp + (size_t)(gp0 + p) * 128 + c2);
                const unsigned short h0 = f2bf(u.x), h1 = f2bf(u.y);
                const unsigned short l0 = f2bf(u.x - bf2f(h0)), l1 = f2bf(u.y - bf2f(h1));
                ((unsigned*)shB)[p * 68 + (c2 >> 1)] = (unsigned)h0 | ((unsigned)h1 << 16);
                ((unsigned*)slB)[p * 68 + (c2 >> 1)] = (unsigned)l0 | ((unsigned)l1 << 16);
            }
        }
        __syncthreads();
        if (ot < nOt) {
            #pragma unroll
            for (int pt = 0; pt < 4; ++pt) {
                floatx4 a = {0.f, 0.f, 0.f, 0.f};
                const int roff = (pt * 16 + nrow) * 136 + quad * 8;
                #pragma unroll
                for (int s = 0; s < 4; ++s) {
                    const bf16x8 BhA = *(const bf16x8*)(shA + roff + s * 32);
                    const bf16x8 BlA = *(const bf16x8*)(slA + roff + s * 32);
                    a = __builtin_amdgcn_mfma_f32_16x16x32_bf16(AhA[s], BhA, a, 0, 0, 0);
                    a = __builtin_amdgcn_mfma_f32_16x16x32_bf16(AlA[s], BhA, a, 0, 0, 0);
                    a = __builtin_amdgcn_mfma_f32_16x16x32_bf16(AhA[s], BlA, a, 0, 0, 0);
                    if (dual) {
                        const unsigned short* shB = sm + 2 * 64 * 136;
                        const unsigned short* slB = sm + 3 * 64 * 136;
                        const bf16x8 BhB = *(const bf16x8*)(shB + roff + s * 32);
                        const bf16x8 BlB = *(const bf16x8*)(slB + roff + s * 32);
                        a = __builtin_amdgcn_mfma_f32_16x16x32_bf16(AhB[s], BhB, a, 0, 0, 0);
                        a = __builtin_amdgcn_mfma_f32_16x16x32_bf16(AlB[s], BhB, a, 0, 0, 0);
                        a = __builtin_amdgcn_mfma_f32_16x16x32_bf16(AhB[s], BlB, a, 0, 0, 0);
                    }
                }
                acc[hlf * 4 + pt] = a;
            }
        }
    }

    // ---- fused LN over the 128-w row + store ----
    if (ot < nOt) {
        float wgt[8], bia[8];
        #pragma unroll
        for (int i = 0; i < 8; ++i) {
            const int w = (i >> 2) * 64 + (i & 3) * 16 + nrow;
            wgt[i] = lnw[w];
            bia[i] = lnb[w];
        }
        #pragma unroll
        for (int r = 0; r < 4; ++r) {
            const int o = ot * 16 + quad * 4 + r;
            if (o < O) {
                float s = 0.f, q = 0.f;
                #pragma unroll
                for (int i = 0; i < 8; ++i) {
                    const float v = acc[i][r];
                    s += v; q = fmaf(v, v, q);
                }
                s += __shfl_xor(s, 1); q += __shfl_xor(q, 1);
                s += __shfl_xor(s, 2); q += __shfl_xor(q, 2);
                s += __shfl_xor(s, 4); q += __shfl_xor(q, 4);
                s += __shfl_xor(s, 8); q += __shfl_xor(q, 8);
                const float mean = s * (1.f / 128.f);
                const float var  = q * (1.f / 128.f) - mean * mean;
                const float rstd = rsqrtf(var + EPS);
                float* ob = outI + (size_t)o * NPIX + row0;
                #pragma unroll
                for (int i = 0; i < 8; ++i)
                    ob[(i >> 2) * 64 + (i & 3) * 16 + nrow] =
                        (acc[i][r] - mean) * rstd * wgt[i] + bia[i];
            }
        }
    }
}

// ---------------------------------------------------------------------------
extern "C" void kernel_launch(void* const* d_in, const int* in_sizes, int n_in,
                              void* d_out, int out_size, void* d_ws, size_t ws_size,
                              hipStream_t stream)
{
    const float* xin[5];
    for (int i = 0; i < 5; ++i) xin[i] = (const float*)d_in[i];
    const float* b_cw[2] = {(const float*)d_in[5],  (const float*)d_in[11]};
    const float* b_cb[2] = {(const float*)d_in[6],  (const float*)d_in[12]};
    const float* b_ow[2] = {(const float*)d_in[7],  (const float*)d_in[13]};
    const float* b_mw[2] = {(const float*)d_in[8],  (const float*)d_in[14]};
    const float* b_bg[2] = {(const float*)d_in[9],  (const float*)d_in[15]};
    const float* b_bb[2] = {(const float*)d_in[10], (const float*)d_in[16]};
    const float* pw[8];
    for (int i = 0; i < 8; ++i) pw[i] = (const float*)d_in[17 + i];
    const float* lnw = (const float*)d_in[25];
    const float* lnb = (const float*)d_in[26];

    float* W = (float*)d_ws;
    float* out = (float*)d_out;
    unsigned short* wB = (unsigned short*)(W + OFF_WB);
    unsigned short* wC = (unsigned short*)(W + OFF_WC);
    unsigned short* aP = (unsigned short*)(W + OFF_APROJ);

    // Batched (all-5-images-per-stage) layout needs 25,838,912 floats
    // (~103 MB); fall back to per-image serial (22 MB) if ws is smaller.
    const int batched = (ws_size >= 25838912ull * 4ull);
    const size_t NI = batched ? 5 : 1;
    size_t off = OFF_BUFS;
    unsigned* offaB = (unsigned*)(W + off);          off += NI * 294912;
    float*    offwB = W + off;                       off += NI * 589824;
    unsigned short* XH = (unsigned short*)(W + off); off += NI * 1048576;
    unsigned short* YH = (unsigned short*)(W + off); off += NI * 1048576;
    float* BUFB = W + off;                           off += NI * 2097152;
    float* STATS = W + off;

    setup1<<<2178, 256, 0, stream>>>(
        b_cw[0], b_cb[0], b_ow[0], b_mw[0],
        b_cw[1], b_cb[1], b_ow[1], b_mw[1],
        pw[0], pw[1], pw[2], pw[3], pw[4], pw[5], pw[6], pw[7],
        W + OFF_WCOMB, W + OFF_BCOMB, wB, aP, STATS);
    setup2<<<288, 256, 0, stream>>>(W + OFF_WCOMB, wC);

    if (batched) {
        prep_xh<<<dim3(2048, 5), 256, 0, stream>>>(
            xin[0], xin[1], xin[2], xin[3], xin[4], XH);
        conv_offm<false><<<dim3(1024, 5), 512, 0, stream>>>(
            XH, wC, W + OFF_BCOMB, nullptr, nullptr, nullptr, offaB, offwB);
        deform_kernel<false><<<dim3(512, 5), 512, 0, stream>>>(
            XH, offaB, offwB, wB, b_cb[0], STATS, nullptr, nullptr,
            nullptr, YH);
        conv_offm<true><<<dim3(1024, 5), 512, 0, stream>>>(
            YH, wC + 36864, W + OFF_BCOMB + 32, STATS, b_bg[0], b_bb[0],
            offaB, offwB);
        deform_kernel<true><<<dim3(512, 5), 512, 0, stream>>>(
            YH, offaB, offwB, wB + 147456, b_cb[1], STATS, b_bg[0], b_bb[0],
            BUFB, nullptr);
        proj_all<<<dim3(128, 15), 256, 0, stream>>>(
            BUFB, xin[0], xin[1], xin[2], xin[3], xin[4], aP,
            STATS, b_bg[1], b_bb[1], lnw, lnb, out);
    } else {
        static const int Obase[5] = {0, 20, 100, 250, 460};
        for (int img = 0; img < 5; ++img) {
            float* stI = STATS + (size_t)img * 512;
            prep_xh<<<dim3(2048, 1), 256, 0, stream>>>(
                xin[img], xin[img], xin[img], xin[img], xin[img], XH);
            conv_offm<false><<<dim3(1024, 1), 512, 0, stream>>>(
                XH, wC, W + OFF_BCOMB, nullptr, nullptr, nullptr, offaB, offwB);
            deform_kernel<false><<<dim3(512, 1), 512, 0, stream>>>(
                XH, offaB, offwB, wB, b_cb[0], stI, nullptr, nullptr,
                nullptr, YH);
            conv_offm<true><<<dim3(1024, 1), 512, 0, stream>>>(
                YH, wC + 36864, W + OFF_BCOMB + 32, stI, b_bg[0], b_bb[0],
                offaB, offwB);
            deform_kernel<true><<<dim3(512, 1), 512, 0, stream>>>(
                YH, offaB, offwB, wB + 147456, b_cb[1], stI, b_bg[0], b_bb[0],
                BUFB, nullptr);
            // fallback projections: reuse proj_all's per-image y-rows by
            // launching with a single-image y map (img slots 0..)
            // Simplest correct path: emulate with proj_all on a 1-image
            // layout is not possible (lookup tables are batched), so keep a
            // minimal per-image loop using the batched tables via offset 0.
            // NOTE: serial path is correctness fallback only.
            const int yBase[5] = {0, 1, 3, 6, 10};
            const int yCnt[5]  = {1, 2, 3, 4, 5};
            // temporary single-image proj: copy BUFB slot0 + stats slot0 are
            // already in place; launch the relevant y-slice of proj_all.
            // proj_all indexes bufB/stats by img from its tables, so for the
            // serial path we place data in slot `img`? Not allocated.
            // Instead: launch proj_all restricted via grid offset trick is
            // not expressible; use a dedicated small launch per image below.
            (void)yBase; (void)yCnt; (void)Obase;
            // Per-image projection using proj_all's body via a 15-wide grid
            // would read unallocated slots; so in serial mode we simply run
            // proj_all's work for this image by pointing bufB/stats at the
            // slot-0 buffers and using a per-image y-range:
            // y in [yBase[img], yBase[img]+yCnt[img]) with img remapped to 0
            // is not possible without a kernel arg; accept one extra arg:
        }
        // Serial fallback: run proj for all images at the end (BUFB slot 0
        // holds only the last image in serial mode, so the loop above must
        // not be used with proj deferred). To keep the fallback CORRECT we
        // instead re-run the whole pipeline per image with proj inline:
        // (this branch is only taken when ws < 103 MB, which the harness
        // does not do; retained for safety with the straightforward layout)
    }
}

// Round 15
// 498.716 us; speedup vs baseline: 1.0182x; 1.0182x over previous
//
#include <hip/hip_runtime.h>
#include <math.h>

// Problem constants
#define HH 128
#define WW 128
#define CC 128
#define KK 9
#define NPIX 16384           // H*W
#define NELEM 2097152        // NPIX*C
#define EPS 1e-5f

// LDS row stride for gather tiles, in halves. MUST keep row base 16B-aligned
// (mrow*LPAD*2 % 16 == 0) for ds_read_b128: LPAD=1164 (rounds 10-11) broke
// this -> misaligned/split b128 LDS reads -> deform 114->216us. The 5.9M
// SQ_LDS_BANK_CONFLICT at 1160 is the INHERENT serialization of 1024B-wide
// b128 reads -- not fixable. Keep 1160.
#define LPAD 1160
#define LPADD 580            // dwords

// Fixed weight-region layout (float offsets); image buffers laid out at
// runtime with NI = 5 (batched) or 1 (serial fallback) slots.
#define OFF_WCOMB 0          // [2][9][27][128] fp32      = 62208
#define OFF_BCOMB 62208      // [2][32] fp32              = 64
#define OFF_WB    62272      // fp16 B-frag deform w: 2*147456 ushort = 147456 floats
#define OFF_WC    209728     // fp16 B-frag conv w:   2*36864 ushort  = 36864 floats
#define OFF_APROJ 246592     // hi/lo bf16 A-frag proj w: 389120 ushort = 194560 floats
#define OFF_BUFS  441152     // image buffers start here

// Session lessons (rounds 10-14):
//  - No XCD blockIdx swizzle (r10: deform 114->214us).
//  - LPAD must stay 1160 (b128 alignment, r11).
//  - No f16 input prepass in ANY packaging (r5/r14: conv0's f32 gather is
//    L3-resident + prefetchable; prepass adds a serial 60 MB stream).
//  - Deform is mixed latency-bound (VALU 41 / MFMA 9 / Occ 40 / HBM 8.5%);
//    occupancy LDS-capped at 2 blocks/CU by the 74 KB tile. Floor ~100us.

typedef __bf16    bf16x8 __attribute__((ext_vector_type(8)));
typedef _Float16  f16x8  __attribute__((ext_vector_type(8)));
typedef _Float16  f16x2  __attribute__((ext_vector_type(2)));
typedef float     floatx4 __attribute__((ext_vector_type(4)));

__device__ __forceinline__ unsigned short f2bf(float f) {
    unsigned u = __float_as_uint(f);
    return (unsigned short)((u + 0x7FFF + ((u >> 16) & 1)) >> 16);   // RNE
}
__device__ __forceinline__ float bf2f(unsigned short h) {
    return __uint_as_float(((unsigned)h) << 16);
}
__device__ __forceinline__ unsigned short f2h(float f) {
    _Float16 h = (_Float16)f;                                        // v_cvt_f16_f32 (RNE)
    return __builtin_bit_cast(unsigned short, h);
}
__device__ __forceinline__ f16x2 h2bc(unsigned u) {
    return __builtin_bit_cast(f16x2, u);
}
// packed BN+ReLU: v_pk_fma_f16 + v_pk_max_f16
__device__ __forceinline__ f16x2 nrm2(f16x2 g, f16x2 sc, f16x2 sh) {
    f16x2 r = g * sc + sh;
    const f16x2 z = {(_Float16)0.f, (_Float16)0.f};
    return __builtin_elementwise_max(r, z);
}

// ---------------------------------------------------------------------------
// setup1: all independent setup work in ONE launch (launch-gap reduction):
//   blocks [0,704)    conv-compose layer 0 (wcomb/bcomb/wB swizzle)
//   blocks [704,1408) conv-compose layer 1
//   blocks [1408,2168) projA hi/lo bf16 A-fragment planes (760 blocks)
//   blocks [2168,2178) zero the STATS region (2560 floats)
// ---------------------------------------------------------------------------
__global__ __launch_bounds__(256) void setup1(
    const float* __restrict__ cw0, const float* __restrict__ cb0,
    const float* __restrict__ ow0, const float* __restrict__ mw0,
    const float* __restrict__ cw1, const float* __restrict__ cb1,
    const float* __restrict__ ow1, const float* __restrict__ mw1,
    const float* __restrict__ s0, const float* __restrict__ s1,
    const float* __restrict__ s2, const float* __restrict__ s3,
    const float* __restrict__ s4, const float* __restrict__ s5,
    const float* __restrict__ s6, const float* __restrict__ s7,
    float* __restrict__ wcombB, float* __restrict__ bcombB,
    unsigned short* __restrict__ wBB, unsigned short* __restrict__ aP,
    float* __restrict__ stats)
{
    const int b = blockIdx.x;
    if (b < 1408) {
        const int layer = (b >= 704);
        const float* cw = layer ? cw1 : cw0;
        const float* cb = layer ? cb1 : cb0;
        const float* ow = layer ? ow1 : ow0;
        const float* mw = layer ? mw1 : mw0;
        float* wcomb = wcombB + layer * 31104;
        float* bcomb = bcombB + layer * 32;
        unsigned short* wBu = wBB + layer * 147456;
        int tid = (b - layer * 704) * 256 + threadIdx.x;
        if (tid < 31104) {
            int c = tid & 127;
            int o = (tid >> 7) % 27;
            int k = tid / 3456;                  // k in [0,9)
            const float* sel = (o < 18) ? (ow + o * 128) : (mw + (o - 18) * 128);
            float v = 0.f;
            for (int cp = 0; cp < 128; ++cp)
                v = fmaf(sel[cp], cw[cp * 1152 + c * 9 + k], v);
            wcomb[tid] = v;                      // wcomb[k][o][c]
        } else if (tid < 31104 + 27) {
            int o = tid - 31104;
            const float* sel = (o < 18) ? (ow + o * 128) : (mw + (o - 18) * 128);
            float v = 0.f;
            for (int cp = 0; cp < 128; ++cp)
                v = fmaf(sel[cp], cb[cp], v);
            bcomb[o] = v;
        } else if (tid >= 32768 && tid < 32768 + 147456) {
            int i = tid - 32768;
            int j    = i & 7;
            int lane = (i >> 3) & 63;
            int t    = (i >> 9) & 7;
            int s    = i >> 12;                  // 0..35
            int kc   = s * 32 + ((lane >> 4) << 3) + j;
            int o    = t * 16 + (lane & 15);
            wBu[i] = f2h(cw[o * 1152 + (kc & 127) * 9 + (kc >> 7)]);
        }
    } else if (b < 2168) {
        const int Os[8]   = {20, 80, 150, 150, 210, 210, 308, 308};
        const int nOt[8]  = {2, 5, 10, 10, 14, 14, 20, 20};
        const int tOff[8] = {0, 4096, 14336, 34816, 55296, 83968, 112640, 153600};
        const int dOff[8] = {0, 8192, 28672, 69632, 110592, 167936, 225280, 307200};
        int tid = (b - 1408) * 256 + threadIdx.x;     // < 194560
        int m = 0;
        #pragma unroll
        for (int q = 1; q < 8; ++q) if (tid >= tOff[q]) m = q;
        const float* src;
        switch (m) {
            case 0: src = s0; break; case 1: src = s1; break;
            case 2: src = s2; break; case 3: src = s3; break;
            case 4: src = s4; break; case 5: src = s5; break;
            case 6: src = s6; break; default: src = s7; break;
        }
        int i = tid - tOff[m];
        int j    = i & 7;
        int lane = (i >> 3) & 63;
        int s    = (i >> 9) & 3;
        int ot   = i >> 11;
        int o = ot * 16 + (lane & 15);
        int c = s * 32 + ((lane >> 4) << 3) + j;
        float v = (o < Os[m]) ? src[o * 128 + c] : 0.f;
        unsigned short h = f2bf(v);
        unsigned short l = f2bf(v - bf2f(h));
        const int hiSize = nOt[m] * 2048;
        aP[dOff[m] + i] = h;
        aP[dOff[m] + hiSize + i] = l;
    } else {
        const int i = (b - 2168) * 256 + threadIdx.x;
        if (i < 2560) stats[i] = 0.f;
    }
}

// ---------------------------------------------------------------------------
// setup2: both layers' composed-conv-weight B-fragment swizzles (reads wcomb
// produced by setup1, so it must be a separate dispatch).
// ---------------------------------------------------------------------------
__global__ __launch_bounds__(256) void setup2(
    const float* __restrict__ wcombB, unsigned short* __restrict__ wCB)
{
    const int b = blockIdx.x;
    const int layer = (b >= 144);
    const float* wcomb = wcombB + layer * 31104;
    unsigned short* wC = wCB + layer * 36864;
    int i = (b - layer * 144) * 256 + threadIdx.x;
    if (i >= 36864) return;
    int j    = i & 7;
    int lane = (i >> 3) & 63;
    int grp  = i >> 9;                       // s*2 + t
    int t = grp & 1, s = grp >> 1;
    int kc = s * 32 + ((lane >> 4) << 3) + j;
    int o  = t * 16 + (lane & 15);
    int c = kc & 127, k = kc >> 7;
    float v = (o < 27) ? wcomb[k * 3456 + o * 128 + c] : 0.f;
    wC[i] = f2h(v);
}

// ---------------------------------------------------------------------------
// conv_offm, 512 threads (8 waves), 16 px/block, blockIdx.y = image.
// FH=false: raw f32 input; center tap side-writes the f16 image (free).
// FH=true: raw f16 input + packed BN+ReLU fused into the gather.
// MFMA: wave = (t = wid&1, kq = wid>>1), 9 K-steps with B prefetch; 4-way
// K-reduction through recycled LDS. Epilogue emits packed gather descriptors.
// ---------------------------------------------------------------------------
template <bool FH>
__global__ __launch_bounds__(512, 8) void conv_offm(
    const float* __restrict__ xi0, const float* __restrict__ xi1,
    const float* __restrict__ xi2, const float* __restrict__ xi3,
    const float* __restrict__ xi4,
    const unsigned short* __restrict__ xhB,
    unsigned short* __restrict__ xhoutB,
    const unsigned short* __restrict__ wC, const float* __restrict__ bcomb,
    const float* __restrict__ stB, const float* __restrict__ bg,
    const float* __restrict__ bb,
    unsigned* __restrict__ offaB, float* __restrict__ offwB)
{
    __shared__ unsigned short smp[16 * LPAD];   // 37120 B -> 4 blocks/CU
    float* red  = (float*)smp;                  // recycled: [3][2][16][16] = 1536 f
    float* vals = red + 1536;                   // recycled: [16][33]       = 528 f
    float* maskL = red;                         // recycled again: [16][9]

    const int img  = blockIdx.y;
    const int gp0  = blockIdx.x * 16;
    const int lane = threadIdx.x & 63;
    const int wid  = threadIdx.x >> 6;          // 0..7
    const int half = lane >> 5;
    const int cl   = lane & 31;                 // channel-quad index

    const float* xf = xi0;
    if (img == 1) xf = xi1; else if (img == 2) xf = xi2;
    else if (img == 3) xf = xi3; else if (img == 4) xf = xi4;
    const float4* x4p = (const float4*)xf;
    const uint2*  x2  = (const uint2*)xhB + (size_t)img * 524288;
    uint2*  offa2 = (uint2*)offaB + (size_t)img * 147456;
    float4* offw4 = (float4*)offwB + (size_t)img * 147456;

    f16x2 scp0, scp1, shp0, shp1;
    if constexpr (FH) {
        const float* st = stB + (size_t)img * 512;
        float sc4[4], sh4[4];
        #pragma unroll
        for (int j = 0; j < 4; ++j) {
            const int c = cl * 4 + j;
            const float mean = st[c] * (1.f / 16384.f);
            const float var  = st[128 + c] * (1.f / 16384.f) - mean * mean;
            const float rstd = rsqrtf(var + EPS);
            sc4[j] = bg[c] * rstd;
            sh4[j] = bb[c] - mean * sc4[j];
        }
        scp0 = (f16x2){(_Float16)sc4[0], (_Float16)sc4[1]};
        scp1 = (f16x2){(_Float16)sc4[2], (_Float16)sc4[3]};
        shp0 = (f16x2){(_Float16)sh4[0], (_Float16)sh4[1]};
        shp1 = (f16x2){(_Float16)sh4[2], (_Float16)sh4[3]};
    }

    // ---- gather: wave wid handles pixels 2*wid + half ----
    {
        const int pl = wid * 2 + half;
        const int gp = gp0 + pl;
        const int h0 = gp >> 7, w0 = gp & 127;
        unsigned* dstq = (unsigned*)smp + pl * LPADD + cl * 2;
        #pragma unroll
        for (int k = 0; k < 9; ++k) {
            const int ny = h0 + k / 3 - 1;
            const int nx = w0 + k % 3 - 1;
            const int cy = min(max(ny, 0), 127);
            const int cx = min(max(nx, 0), 127);
            const bool ok = ((unsigned)ny < 128u) & ((unsigned)nx < 128u);
            unsigned d0, d1;
            if constexpr (FH) {
                const uint2 g = x2[(((cy << 7) + cx) << 5) + cl];
                const f16x2 pa = nrm2(h2bc(g.x), scp0, shp0);
                const f16x2 pb = nrm2(h2bc(g.y), scp1, shp1);
                d0 = __builtin_bit_cast(unsigned, pa);
                d1 = __builtin_bit_cast(unsigned, pb);
            } else {
                const float4 v = x4p[(((cy << 7) + cx) << 5) + cl];
                d0 = (unsigned)f2h(v.x) | ((unsigned)f2h(v.y) << 16);
                d1 = (unsigned)f2h(v.z) | ((unsigned)f2h(v.w) << 16);
            }
            d0 = ok ? d0 : 0u;
            d1 = ok ? d1 : 0u;
            if constexpr (!FH) {
                if (k == 4) {  // center tap == this pixel: emit f16 image
                    uint2* xo = (uint2*)xhoutB + (size_t)img * 524288;
                    xo[(size_t)gp * 32 + cl] = make_uint2(d0, d1);
                }
            }
            *(uint2*)(dstq + k * 64) = make_uint2(d0, d1);
        }
    }
    __syncthreads();

    // ---- MFMA: wave = (t = wid&1, kq = wid>>1), 9 K-steps each ----
    const int t    = wid & 1;
    const int kq   = wid >> 1;
    const int mrow = lane & 15;
    const int quad = lane >> 4;
    floatx4 acc = {0.f, 0.f, 0.f, 0.f};
    const unsigned short* arow = smp + mrow * LPAD + quad * 8;
    const unsigned short* bbase = wC + t * 512 + (lane << 3);
    f16x8 b = *(const f16x8*)(bbase + (kq * 9) * 1024);
    #pragma unroll
    for (int j = 0; j < 9; ++j) {
        const int s = kq * 9 + j;
        f16x8 nb;
        if (j < 8) nb = *(const f16x8*)(bbase + (s + 1) * 1024);
        const f16x8 a = *(const f16x8*)(arow + s * 32);
        acc = __builtin_amdgcn_mfma_f32_16x16x32_f16(a, b, acc, 0, 0, 0);
        if (j < 8) b = nb;
    }
    __syncthreads();   // all smp reads done; safe to recycle as red/vals

    // D: row (pixel) = quad*4+r, col (channel) = lane&15
    if (kq > 0) {
        #pragma unroll
        for (int r = 0; r < 4; ++r)
            red[(((kq - 1) * 2 + t) << 8) + (quad * 4 + r) * 16 + mrow] = acc[r];
    }
    __syncthreads();
    if (kq == 0) {
        #pragma unroll
        for (int r = 0; r < 4; ++r) {
            const int rc = (quad * 4 + r) * 16 + mrow;
            const float sv = acc[r] + red[(t << 8) + rc]
                           + red[((2 + t) << 8) + rc] + red[((4 + t) << 8) + rc];
            vals[(quad * 4 + r) * 33 + t * 16 + mrow] = sv;
        }
    }
    __syncthreads();

    // ---- epilogue A: lanes < 16 compute softmax masks into maskL ----
    if (threadIdx.x < 16) {
        const int p = threadIdx.x;
        const float* vp = vals + p * 33;
        float e[9], se = 0.f, mx = -1e30f;
        #pragma unroll
        for (int k = 0; k < 9; ++k) {
            e[k] = vp[18 + k] + bcomb[18 + k];
            mx = fmaxf(mx, e[k]);
        }
        #pragma unroll
        for (int k = 0; k < 9; ++k) { e[k] = expf(e[k] - mx); se += e[k]; }
        const float inv = 1.f / se;
        #pragma unroll
        for (int k = 0; k < 9; ++k) maskL[p * 9 + k] = e[k] * inv;
    }
    __syncthreads();

    // ---- epilogue B: 144 threads emit packed gather descriptors ----
    if (threadIdx.x < 144) {
        const int p = threadIdx.x / 9;
        const int k = threadIdx.x - p * 9;
        const int gp = gp0 + p;
        const int hh = gp >> 7, ww = gp & 127;
        const float* vp = vals + p * 33;
        const float py = (float)(hh - 1 + k / 3) + vp[2 * k]     + bcomb[2 * k];
        const float px = (float)(ww - 1 + k % 3) + vp[2 * k + 1] + bcomb[2 * k + 1];
        const float mk = maskL[p * 9 + k];
        const float y0f = floorf(py), x0f = floorf(px);
        const int iy0 = (int)y0f, ix0 = (int)x0f;
        const float wy1 = py - y0f, wy0 = 1.f - wy1;
        const float wx1 = px - x0f, wx0 = 1.f - wx1;
        const int cy0 = min(max(iy0, 0), 127);
        const int cy1 = min(max(iy0 + 1, 0), 127);
        const int cx0 = min(max(ix0, 0), 127);
        const int cx1 = min(max(ix0 + 1, 0), 127);
        const float vy0 = ((unsigned)iy0       < 128u) ? 1.f : 0.f;
        const float vy1 = ((unsigned)(iy0 + 1) < 128u) ? 1.f : 0.f;
        const float vx0 = ((unsigned)ix0       < 128u) ? 1.f : 0.f;
        const float vx1 = ((unsigned)(ix0 + 1) < 128u) ? 1.f : 0.f;
        const float w00 = wy0 * wx0 * vy0 * vx0 * mk;
        const float w01 = wy0 * wx1 * vy0 * vx1 * mk;
        const float w10 = wy1 * wx0 * vy1 * vx0 * mk;
        const float w11 = wy1 * wx1 * vy1 * vx1 * mk;
        const unsigned i00 = (unsigned)((cy0 << 7) | cx0);
        const unsigned i01 = (unsigned)((cy0 << 7) | cx1);
        const unsigned i10 = (unsigned)((cy1 << 7) | cx0);
        const unsigned i11 = (unsigned)((cy1 << 7) | cx1);
        offa2[(size_t)gp * 9 + k] =
            make_uint2(i00 | (i01 << 16), i10 | (i11 << 16));
        offw4[(size_t)gp * 9 + k] = make_float4(w00, w01, w10, w11);
    }
}

// ---------------------------------------------------------------------------
// deform, 512 threads (8 waves), 32 px/block, blockIdx.y = image. Gather:
// all 9 descriptor pairs preloaded into registers per pass (r12: breaks the
// per-tap desc->corner serial chain). Corners from the f16 image.
// NORM=false (blk0): no norm, f16 output yh + stats at img*512. NORM=true
// (blk1): packed-f16 BN+ReLU per corner; f32 output, stats at img*512+256.
// MFMA: wave wid owns N-tile wid over M=32 px as 2 M-subtiles; 6-deep B
// prefetch. Epilogue: store + fused sum/sumsq stats.
// ---------------------------------------------------------------------------
template <bool NORM>
__global__ __launch_bounds__(512, 4) void deform_kernel(
    const unsigned short* __restrict__ xhB,
    const unsigned* __restrict__ offaB, const float* __restrict__ offwB,
    const unsigned short* __restrict__ wBu, const float* __restrict__ cb,
    float* __restrict__ stB, const float* __restrict__ bg,
    const float* __restrict__ bb,
    float* __restrict__ yB, unsigned short* __restrict__ yhB)
{
    __shared__ unsigned short smp[32 * LPAD];   // 74240 B -> 2 blocks/CU

    const int img  = blockIdx.y;
    const int gp0  = blockIdx.x * 32;
    const int lane = threadIdx.x & 63;
    const int wid  = threadIdx.x >> 6;          // 0..7
    const int half = lane >> 5;
    const int cl   = lane & 31;
    const uint2* x2 = (const uint2*)xhB + (size_t)img * 524288;
    const uint2*  apB = (const uint2*)offaB + (size_t)img * 147456;
    const float4* wpB = (const float4*)offwB + (size_t)img * 147456;

    f16x2 scp0, scp1, shp0, shp1;
    if constexpr (NORM) {
        const float* stp = stB + (size_t)img * 512;
        float sc4[4], sh4[4];
        #pragma unroll
        for (int j = 0; j < 4; ++j) {
            const int c = cl * 4 + j;
            const float mean = stp[c] * (1.f / 16384.f);
            const float var  = stp[128 + c] * (1.f / 16384.f) - mean * mean;
            const float rstd = rsqrtf(var + EPS);
            sc4[j] = bg[c] * rstd;
            sh4[j] = bb[c] - mean * sc4[j];
        }
        scp0 = (f16x2){(_Float16)sc4[0], (_Float16)sc4[1]};
        scp1 = (f16x2){(_Float16)sc4[2], (_Float16)sc4[3]};
        shp0 = (f16x2){(_Float16)sh4[0], (_Float16)sh4[1]};
        shp1 = (f16x2){(_Float16)sh4[2], (_Float16)sh4[3]};
    }

    // ---- phase 1: wave wid gathers pixels wid*4 + pass*2 + half ----
    for (int pass = 0; pass < 2; ++pass) {
        const int pl = wid * 4 + pass * 2 + half;
        const size_t tb = (size_t)(gp0 + pl) * 9;
        const uint2*  ap = apB + tb;
        const float4* wp = wpB + tb;
        unsigned* dstq = (unsigned*)smp + pl * LPADD + cl * 2;
        // preload all descriptors (issues 18 loads back-to-back)
        uint2  aq[9];
        float4 wq[9];
        #pragma unroll
        for (int k = 0; k < 9; ++k) { aq[k] = ap[k]; wq[k] = wp[k]; }
        #pragma unroll
        for (int k = 0; k < 9; ++k) {
            const uint2  a = aq[k];
            const float4 w = wq[k];
            const int i00 = (int)(a.x & 0xFFFFu) << 5;
            const int i01 = (int)(a.x >> 16) << 5;
            const int i10 = (int)(a.y & 0xFFFFu) << 5;
            const int i11 = (int)(a.y >> 16) << 5;
            const uint2 G00 = x2[i00 + cl];
            const uint2 G01 = x2[i01 + cl];
            const uint2 G10 = x2[i10 + cl];
            const uint2 G11 = x2[i11 + cl];
            f16x2 a00 = h2bc(G00.x), b00 = h2bc(G00.y);
            f16x2 a01 = h2bc(G01.x), b01 = h2bc(G01.y);
            f16x2 a10 = h2bc(G10.x), b10 = h2bc(G10.y);
            f16x2 a11 = h2bc(G11.x), b11 = h2bc(G11.y);
            if constexpr (NORM) {
                a00 = nrm2(a00, scp0, shp0); b00 = nrm2(b00, scp1, shp1);
                a01 = nrm2(a01, scp0, shp0); b01 = nrm2(b01, scp1, shp1);
                a10 = nrm2(a10, scp0, shp0); b10 = nrm2(b10, scp1, shp1);
                a11 = nrm2(a11, scp0, shp0); b11 = nrm2(b11, scp1, shp1);
            }
            // f32 accumulation directly from packed halves (fma_mix)
            const float s0 = fmaf(w.x, (float)a00.x, fmaf(w.y, (float)a01.x,
                             fmaf(w.z, (float)a10.x, w.w * (float)a11.x)));
            const float s1 = fmaf(w.x, (float)a00.y, fmaf(w.y, (float)a01.y,
                             fmaf(w.z, (float)a10.y, w.w * (float)a11.y)));
            const float s2 = fmaf(w.x, (float)b00.x, fmaf(w.y, (float)b01.x,
                             fmaf(w.z, (float)b10.x, w.w * (float)b11.x)));
            const float s3 = fmaf(w.x, (float)b00.y, fmaf(w.y, (float)b01.y,
                             fmaf(w.z, (float)b10.y, w.w * (float)b11.y)));
            const unsigned d0 = (unsigned)f2h(s0) | ((unsigned)f2h(s1) << 16);
            const unsigned d1 = (unsigned)f2h(s2) | ((unsigned)f2h(s3) << 16);
            *(uint2*)(dstq + k * 64) = make_uint2(d0, d1);
        }
    }
    __syncthreads();

    // ---- phase 2: wave wid owns N-tile wid, M = 2 subtiles, K = 36 ----
    const int mrow = lane & 15;
    const int quad = lane >> 4;
    const unsigned short* arow0 = smp + mrow * LPAD + quad * 8;
    const unsigned short* arow1 = arow0 + 16 * LPAD;
    const unsigned short* bbase = wBu + wid * 512 + (lane << 3);
    floatx4 acc0 = {0.f, 0.f, 0.f, 0.f};
    floatx4 acc1 = {0.f, 0.f, 0.f, 0.f};
    f16x8 bq0 = *(const f16x8*)(bbase);
    f16x8 bq1 = *(const f16x8*)(bbase + 4096);
    f16x8 bq2 = *(const f16x8*)(bbase + 2 * 4096);
    f16x8 bq3 = *(const f16x8*)(bbase + 3 * 4096);
    f16x8 bq4 = *(const f16x8*)(bbase + 4 * 4096);
    f16x8 bq5 = *(const f16x8*)(bbase + 5 * 4096);
    #pragma unroll
    for (int s = 0; s < 36; ++s) {
        f16x8 nb;
        if (s < 30) nb = *(const f16x8*)(bbase + (size_t)(s + 6) * 4096);
        const f16x8 a0 = *(const f16x8*)(arow0 + s * 32);
        const f16x8 a1 = *(const f16x8*)(arow1 + s * 32);
        acc0 = __builtin_amdgcn_mfma_f32_16x16x32_f16(a0, bq0, acc0, 0, 0, 0);
        acc1 = __builtin_amdgcn_mfma_f32_16x16x32_f16(a1, bq0, acc1, 0, 0, 0);
        bq0 = bq1; bq1 = bq2; bq2 = bq3; bq3 = bq4; bq4 = bq5;
        if (s < 30) bq5 = nb;
    }

    // ---- epilogue: store + per-channel stats (channel n = wid*16+mrow) ----
    const int n = wid * 16 + mrow;
    const float bias = cb[n];
    float ssum = 0.f, qsum = 0.f;
    #pragma unroll
    for (int r = 0; r < 4; ++r) {
        const float v0 = acc0[r] + bias;
        const float v1 = acc1[r] + bias;
        if constexpr (!NORM) {
            unsigned short* yh = yhB + (size_t)img * 2097152;
            yh[(size_t)(gp0 + quad * 4 + r) * 128 + n]      = f2h(v0);
            yh[(size_t)(gp0 + 16 + quad * 4 + r) * 128 + n] = f2h(v1);
        } else {
            float* y = yB + (size_t)img * 2097152;
            y[(size_t)(gp0 + quad * 4 + r) * 128 + n]      = v0;
            y[(size_t)(gp0 + 16 + quad * 4 + r) * 128 + n] = v1;
        }
        ssum += v0 + v1;
        qsum = fmaf(v0, v0, qsum);
        qsum = fmaf(v1, v1, qsum);
    }
    ssum += __shfl_xor(ssum, 16); qsum += __shfl_xor(qsum, 16);
    ssum += __shfl_xor(ssum, 32); qsum += __shfl_xor(qsum, 32);
    if (quad == 0) {
        float* stw = stB + (size_t)img * 512 + (NORM ? 256 : 0);
        atomicAdd(&stw[n], ssum);
        atomicAdd(&stw[128 + n], qsum);
    }
}

// ---------------------------------------------------------------------------
// proj_all: ALL 5 images' 1x1 projections + fused final LN in ONE dispatch.
// blockIdx.y in [0,15) maps to (img, ot-group) via lookup. DUAL (second
// GEMM from the raw input) is a block-uniform runtime branch for img>=2.
// ---------------------------------------------------------------------------
__global__ __launch_bounds__(256) void proj_all(
    const float* __restrict__ bufB,
    const float* __restrict__ xi0, const float* __restrict__ xi1,
    const float* __restrict__ xi2, const float* __restrict__ xi3,
    const float* __restrict__ xi4,
    const unsigned short* __restrict__ aP,
    const float* __restrict__ stats, const float* __restrict__ bgn,
    const float* __restrict__ bbn,
    const float* __restrict__ lnw, const float* __restrict__ lnb,
    float* __restrict__ out)
{
    const int yImg[15]  = {0,1,1,2,2,2,3,3,3,3,4,4,4,4,4};
    const int yOtg[15]  = {0,0,1,0,1,2,0,1,2,3,0,1,2,3,4};
    const int OcntT[5]  = {20, 80, 150, 210, 308};
    const int ObaseT[5] = {0, 20, 100, 250, 460};
    const int aOffAT[5] = {0, 8192, 28672, 110592, 225280};
    const int aOffBT[5] = {0, 0, 69632, 167936, 307200};
    const int hiSzT[5]  = {4096, 10240, 20480, 28672, 40960};

    const int ylin = blockIdx.y;
    const int img  = yImg[ylin];
    const int otg  = yOtg[ylin];
    const bool dual = (img >= 2);
    const int O = OcntT[img];
    const int hiSize = hiSzT[img];
    const float* xc = bufB + (size_t)img * 2097152;
    const float* xp = xi0;
    if (img == 1) xp = xi1; else if (img == 2) xp = xi2;
    else if (img == 3) xp = xi3; else if (img == 4) xp = xi4;
    const unsigned short* aPA = aP + aOffAT[img];
    const unsigned short* aPB = aP + aOffBT[img];
    const float* stn = stats + (size_t)img * 512 + 256;
    float* outI = out + (size_t)ObaseT[img] * NPIX;

    __shared__ unsigned short sm[4 * 64 * 136];
    unsigned short* shA = sm;
    unsigned short* slA = sm + 64 * 136;
    const int row0 = blockIdx.x * 128;          // one full h-row

    const int lane = threadIdx.x & 63;
    const int wid  = threadIdx.x >> 6;
    const int quad = lane >> 4;
    const int nrow = lane & 15;
    const int nOt  = (O + 15) >> 4;
    const int ot   = otg * 4 + wid;

    bf16x8 AhA[4], AlA[4], AhB[4], AlB[4];
    if (ot < nOt) {
        #pragma unroll
        for (int s = 0; s < 4; ++s) {
            const int idx = ((ot * 4 + s) * 64 + lane) * 8;
            AhA[s] = *(const bf16x8*)(aPA + idx);
            AlA[s] = *(const bf16x8*)(aPA + hiSize + idx);
            if (dual) {
                AhB[s] = *(const bf16x8*)(aPB + idx);
                AlB[s] = *(const bf16x8*)(aPB + hiSize + idx);
            }
        }
    }

    floatx4 acc[8];
    #pragma unroll
    for (int i = 0; i < 8; ++i) acc[i] = (floatx4){0.f, 0.f, 0.f, 0.f};

    #pragma unroll
    for (int hlf = 0; hlf < 2; ++hlf) {
        if (hlf) __syncthreads();               // prev GEMM reads done
        const int gp0 = row0 + hlf * 64;
        for (int i = threadIdx.x; i < 4096; i += 256) {
            const int p = i >> 6, c2 = (i & 63) * 2;
            float2 v = *(const float2*)(xc + (size_t)(gp0 + p) * 128 + c2);
            #pragma unroll
            for (int j = 0; j < 2; ++j) {
                const int c = c2 + j;
                const float mean = stn[c] * (1.f / 16384.f);
                const float var  = stn[128 + c] * (1.f / 16384.f) - mean * mean;
                const float rstd = rsqrtf(var + EPS);
                const float scn = bgn[c] * rstd;
                const float shn = bbn[c] - mean * scn;
                float vv = j ? v.y : v.x;
                vv = fmaxf(fmaf(vv, scn, shn), 0.f);
                if (j) v.y = vv; else v.x = vv;
            }
            {
                const unsigned short h0 = f2bf(v.x), h1 = f2bf(v.y);
                const unsigned short l0 = f2bf(v.x - bf2f(h0)), l1 = f2bf(v.y - bf2f(h1));
                ((unsigned*)shA)[p * 68 + (c2 >> 1)] = (unsigned)h0 | ((unsigned)h1 << 16);
                ((unsigned*)slA)[p * 68 + (c2 >> 1)] = (unsigned)l0 | ((unsigned)l1 << 16);
            }
            if (dual) {
                unsigned short* shB = sm + 2 * 64 * 136;
                unsigned short* slB = sm + 3 * 64 * 136;
                const float2 u = *(const float2*)(xp + (size_t)(gp0 + p) * 128 + c2);
                const unsigned short h0 = f2bf(u.x), h1 = f2bf(u.y);
                const unsigned short l0 = f2bf(u.x - bf2f(h0)), l1 = f2bf(u.y - bf2f(h1));
                ((unsigned*)shB)[p * 68 + (c2 >> 1)] = (unsigned)h0 | ((unsigned)h1 << 16);
                ((unsigned*)slB)[p * 68 + (c2 >> 1)] = (unsigned)l0 | ((unsigned)l1 << 16);
            }
        }
        __syncthreads();
        if (ot < nOt) {
            #pragma unroll
            for (int pt = 0; pt < 4; ++pt) {
                floatx4 a = {0.f, 0.f, 0.f, 0.f};
                const int roff = (pt * 16 + nrow) * 136 + quad * 8;
                #pragma unroll
                for (int s = 0; s < 4; ++s) {
                    const bf16x8 BhA = *(const bf16x8*)(shA + roff + s * 32);
                    const bf16x8 BlA = *(const bf16x8*)(slA + roff + s * 32);
                    a = __builtin_amdgcn_mfma_f32_16x16x32_bf16(AhA[s], BhA, a, 0, 0, 0);
                    a = __builtin_amdgcn_mfma_f32_16x16x32_bf16(AlA[s], BhA, a, 0, 0, 0);
                    a = __builtin_amdgcn_mfma_f32_16x16x32_bf16(AhA[s], BlA, a, 0, 0, 0);
                    if (dual) {
                        const unsigned short* shB = sm + 2 * 64 * 136;
                        const unsigned short* slB = sm + 3 * 64 * 136;
                        const bf16x8 BhB = *(const bf16x8*)(shB + roff + s * 32);
                        const bf16x8 BlB = *(const bf16x8*)(slB + roff + s * 32);
                        a = __builtin_amdgcn_mfma_f32_16x16x32_bf16(AhB[s], BhB, a, 0, 0, 0);
                        a = __builtin_amdgcn_mfma_f32_16x16x32_bf16(AlB[s], BhB, a, 0, 0, 0);
                        a = __builtin_amdgcn_mfma_f32_16x16x32_bf16(AhB[s], BlB, a, 0, 0, 0);
                    }
                }
                acc[hlf * 4 + pt] = a;
            }
        }
    }

    // ---- fused LN over the 128-w row + store ----
    if (ot < nOt) {
        float wgt[8], bia[8];
        #pragma unroll
        for (int i = 0; i < 8; ++i) {
            const int w = (i >> 2) * 64 + (i & 3) * 16 + nrow;
            wgt[i] = lnw[w];
            bia[i] = lnb[w];
        }
        #pragma unroll
        for (int r = 0; r < 4; ++r) {
            const int o = ot * 16 + quad * 4 + r;
            if (o < O) {
                float s = 0.f, q = 0.f;
                #pragma unroll
                for (int i = 0; i < 8; ++i) {
                    const float v = acc[i][r];
                    s += v; q = fmaf(v, v, q);
                }
                s += __shfl_xor(s, 1); q += __shfl_xor(q, 1);
                s += __shfl_xor(s, 2); q += __shfl_xor(q, 2);
                s += __shfl_xor(s, 4); q += __shfl_xor(q, 4);
                s += __shfl_xor(s, 8); q += __shfl_xor(q, 8);
                const float mean = s * (1.f / 128.f);
                const float var  = q * (1.f / 128.f) - mean * mean;
                const float rstd = rsqrtf(var + EPS);
                float* ob = outI + (size_t)o * NPIX + row0;
                #pragma unroll
                for (int i = 0; i < 8; ++i)
                    ob[(i >> 2) * 64 + (i & 3) * 16 + nrow] =
                        (acc[i][r] - mean) * rstd * wgt[i] + bia[i];
            }
        }
    }
}

// ---------------------------------------------------------------------------
// proj_kernel (template): retained for the serial fallback path only.
// ---------------------------------------------------------------------------
template <bool DUAL>
__global__ __launch_bounds__(256) void proj_kernel(
    const float* __restrict__ xc, const float* __restrict__ xp,
    const unsigned short* __restrict__ aPA, const unsigned short* __restrict__ aPB,
    const float* __restrict__ stn, const float* __restrict__ bgn,
    const float* __restrict__ bbn,
    const float* __restrict__ lnw, const float* __restrict__ lnb,
    float* __restrict__ out, int O, int hiSize)
{
    __shared__ unsigned short sm[(DUAL ? 4 : 2) * 64 * 136];
    unsigned short* shA = sm;
    unsigned short* slA = sm + 64 * 136;
    const int row0 = blockIdx.x * 128;

    const int lane = threadIdx.x & 63;
    const int wid  = threadIdx.x >> 6;
    const int quad = lane >> 4;
    const int nrow = lane & 15;
    const int nOt  = (O + 15) >> 4;
    const int ot   = blockIdx.y * 4 + wid;

    bf16x8 AhA[4], AlA[4], AhB[4], AlB[4];
    if (ot < nOt) {
        #pragma unroll
        for (int s = 0; s < 4; ++s) {
            const int idx = ((ot * 4 + s) * 64 + lane) * 8;
            AhA[s] = *(const bf16x8*)(aPA + idx);
            AlA[s] = *(const bf16x8*)(aPA + hiSize + idx);
            if constexpr (DUAL) {
                AhB[s] = *(const bf16x8*)(aPB + idx);
                AlB[s] = *(const bf16x8*)(aPB + hiSize + idx);
            }
        }
    }

    floatx4 acc[8];
    #pragma unroll
    for (int i = 0; i < 8; ++i) acc[i] = (floatx4){0.f, 0.f, 0.f, 0.f};

    #pragma unroll
    for (int hlf = 0; hlf < 2; ++hlf) {
        if (hlf) __syncthreads();
        const int gp0 = row0 + hlf * 64;
        for (int i = threadIdx.x; i < 4096; i += 256) {
            const int p = i >> 6, c2 = (i & 63) * 2;
            float2 v = *(const float2*)(xc + (size_t)(gp0 + p) * 128 + c2);
            #pragma unroll
            for (int j = 0; j < 2; ++j) {
                const int c = c2 + j;
                const float mean = stn[c] * (1.f / 16384.f);
                const float var  = stn[128 + c] * (1.f / 16384.f) - mean * mean;
                const float rstd = rsqrtf(var + EPS);
                const float scn = bgn[c] * rstd;
                const float shn = bbn[c] - mean * scn;
                float vv = j ? v.y : v.x;
                vv = fmaxf(fmaf(vv, scn, shn), 0.f);
                if (j) v.y = vv; else v.x = vv;
            }
            {
                const unsigned short h0 = f2bf(v.x), h1 = f2bf(v.y);
                const unsigned short l0 = f2bf(v.x - bf2f(h0)), l1 = f2bf(v.y - bf2f(h1));
                ((unsigned*)shA)[p * 68 + (c2 >> 1)] = (unsigned)h0 | ((unsigned)h1 << 16);
                ((unsigned*)slA)[p * 68 + (c2 >> 1)] = (unsigned)l0 | ((unsigned)l1 << 16);
            }
            if constexpr (DUAL) {
                unsigned short* shB = sm + 2 * 64 * 136;
                unsigned short* slB = sm + 3 * 64 * 136;
                const float2 u = *(const float2*)(xp + (size_t)(gp0 + p) * 128 + c2);
                const unsigned short h0 = f2bf(u.x), h1 = f2bf(u.y);
                const unsigned short l0 = f2bf(u.x - bf2f(h0)), l1 = f2bf(u.y - bf2f(h1));
                ((unsigned*)shB)[p * 68 + (c2 >> 1)] = (unsigned)h0 | ((unsigned)h1 << 16);
                ((unsigned*)slB)[p * 68 + (c2 >> 1)] = (unsigned)l0 | ((unsigned)l1 << 16);
            }
        }
        __syncthreads();
        if (ot < nOt) {
            #pragma unroll
            for (int pt = 0; pt < 4; ++pt) {
                floatx4 a = {0.f, 0.f, 0.f, 0.f};
                const int roff = (pt * 16 + nrow) * 136 + quad * 8;
                #pragma unroll
                for (int s = 0; s < 4; ++s) {
                    const bf16x8 BhA = *(const bf16x8*)(shA + roff + s * 32);
                    const bf16x8 BlA = *(const bf16x8*)(slA + roff + s * 32);
                    a = __builtin_amdgcn_mfma_f32_16x16x32_bf16(AhA[s], BhA, a, 0, 0, 0);
                    a = __builtin_amdgcn_mfma_f32_16x16x32_bf16(AlA[s], BhA, a, 0, 0, 0);
                    a = __builtin_amdgcn_mfma_f32_16x16x32_bf16(AhA[s], BlA, a, 0, 0, 0);
                    if constexpr (DUAL) {
                        const unsigned short* shB = sm + 2 * 64 * 136;
                        const unsigned short* slB = sm + 3 * 64 * 136;
                        const bf16x8 BhB = *(const bf16x8*)(shB + roff + s * 32);
                        const bf16x8 BlB = *(const bf16x8*)(slB + roff + s * 32);
                        a = __builtin_amdgcn_mfma_f32_16x16x32_bf16(AhB[s], BhB, a, 0, 0, 0);
                        a = __builtin_amdgcn_mfma_f32_16x16x32_bf16(AlB[s], BhB, a, 0, 0, 0);
                        a = __builtin_amdgcn_mfma_f32_16x16x32_bf16(AhB[s], BlB, a, 0, 0, 0);
                    }
                }
                acc[hlf * 4 + pt] = a;
            }
        }
    }

    if (ot < nOt) {
        float wgt[8], bia[8];
        #pragma unroll
        for (int i = 0; i < 8; ++i) {
            const int w = (i >> 2) * 64 + (i & 3) * 16 + nrow;
            wgt[i] = lnw[w];
            bia[i] = lnb[w];
        }
        #pragma unroll
        for (int r = 0; r < 4; ++r) {
            const int o = ot * 16 + quad * 4 + r;
            if (o < O) {
                float s = 0.f, q = 0.f;
                #pragma unroll
                for (int i = 0; i < 8; ++i) {
                    const float v = acc[i][r];
                    s += v; q = fmaf(v, v, q);
                }
                s += __shfl_xor(s, 1); q += __shfl_xor(q, 1);
                s += __shfl_xor(s, 2); q += __shfl_xor(q, 2);
                s += __shfl_xor(s, 4); q += __shfl_xor(q, 4);
                s += __shfl_xor(s, 8); q += __shfl_xor(q, 8);
                const float mean = s * (1.f / 128.f);
                const float var  = q * (1.f / 128.f) - mean * mean;
                const float rstd = rsqrtf(var + EPS);
                float* ob = out + (size_t)o * NPIX + row0;
                #pragma unroll
                for (int i = 0; i < 8; ++i)
                    ob[(i >> 2) * 64 + (i & 3) * 16 + nrow] =
                        (acc[i][r] - mean) * rstd * wgt[i] + bia[i];
            }
        }
    }
}

// ---------------------------------------------------------------------------
extern "C" void kernel_launch(void* const* d_in, const int* in_sizes, int n_in,
                              void* d_out, int out_size, void* d_ws, size_t ws_size,
                              hipStream_t stream)
{
    const float* xin[5];
    for (int i = 0; i < 5; ++i) xin[i] = (const float*)d_in[i];
    const float* b_cw[2] = {(const float*)d_in[5],  (const float*)d_in[11]};
    const float* b_cb[2] = {(const float*)d_in[6],  (const float*)d_in[12]};
    const float* b_ow[2] = {(const float*)d_in[7],  (const float*)d_in[13]};
    const float* b_mw[2] = {(const float*)d_in[8],  (const float*)d_in[14]};
    const float* b_bg[2] = {(const float*)d_in[9],  (const float*)d_in[15]};
    const float* b_bb[2] = {(const float*)d_in[10], (const float*)d_in[16]};
    const float* pw[8];
    for (int i = 0; i < 8; ++i) pw[i] = (const float*)d_in[17 + i];
    const float* lnw = (const float*)d_in[25];
    const float* lnb = (const float*)d_in[26];

    float* W = (float*)d_ws;
    float* out = (float*)d_out;
    unsigned short* wB = (unsigned short*)(W + OFF_WB);
    unsigned short* wC = (unsigned short*)(W + OFF_WC);
    unsigned short* aP = (unsigned short*)(W + OFF_APROJ);

    // Batched (all-5-images-per-stage) layout needs 25,838,912 floats
    // (~103 MB); fall back to per-image serial (22 MB) if ws is smaller.
    const int batched = (ws_size >= 25838912ull * 4ull);
    const size_t NI = batched ? 5 : 1;
    size_t off = OFF_BUFS;
    unsigned* offaB = (unsigned*)(W + off);          off += NI * 294912;
    float*    offwB = W + off;                       off += NI * 589824;
    unsigned short* XH = (unsigned short*)(W + off); off += NI * 1048576;
    unsigned short* YH = (unsigned short*)(W + off); off += NI * 1048576;
    float* BUFB = W + off;                           off += NI * 2097152;
    float* STATS = W + off;

    // consolidated setup: setup1 (independent work + stats zero), then
    // setup2 (convfrag, reads wcomb -> separate dispatch)
    setup1<<<2178, 256, 0, stream>>>(
        b_cw[0], b_cb[0], b_ow[0], b_mw[0],
        b_cw[1], b_cb[1], b_ow[1], b_mw[1],
        pw[0], pw[1], pw[2], pw[3], pw[4], pw[5], pw[6], pw[7],
        W + OFF_WCOMB, W + OFF_BCOMB, wB, aP, STATS);
    setup2<<<288, 256, 0, stream>>>(W + OFF_WCOMB, wC);

    static const int Obase[5] = {0, 20, 100, 250, 460};
    static const int Ocnt[5]  = {20, 80, 150, 210, 308};
    static const int aOffA[5] = {0, 8192, 28672, 110592, 225280};      // c1,c2,c3a,c4a,c5a
    static const int aOffB[5] = {0, 0, 69632, 167936, 307200};         // c3b,c4b,c5b
    static const int hiSz[5]  = {4096, 10240, 20480, 28672, 40960};
    static const int yGrd[5]  = {1, 2, 3, 4, 5};                       // ceil(nOt/4)

    if (batched) {
        conv_offm<false><<<dim3(1024, 5), 512, 0, stream>>>(
            xin[0], xin[1], xin[2], xin[3], xin[4], nullptr, XH,
            wC, W + OFF_BCOMB, nullptr, nullptr, nullptr, offaB, offwB);
        deform_kernel<false><<<dim3(512, 5), 512, 0, stream>>>(
            XH, offaB, offwB, wB, b_cb[0], STATS, nullptr, nullptr,
            nullptr, YH);
        conv_offm<true><<<dim3(1024, 5), 512, 0, stream>>>(
            nullptr, nullptr, nullptr, nullptr, nullptr, YH, nullptr,
            wC + 36864, W + OFF_BCOMB + 32, STATS, b_bg[0], b_bb[0],
            offaB, offwB);
        deform_kernel<true><<<dim3(512, 5), 512, 0, stream>>>(
            YH, offaB, offwB, wB + 147456, b_cb[1], STATS, b_bg[0], b_bb[0],
            BUFB, nullptr);
        proj_all<<<dim3(128, 15), 256, 0, stream>>>(
            BUFB, xin[0], xin[1], xin[2], xin[3], xin[4], aP,
            STATS, b_bg[1], b_bb[1], lnw, lnb, out);
    } else {
        for (int img = 0; img < 5; ++img) {
            float* stI = STATS + (size_t)img * 512;
            conv_offm<false><<<dim3(1024, 1), 512, 0, stream>>>(
                xin[img], xin[img], xin[img], xin[img], xin[img], nullptr, XH,
                wC, W + OFF_BCOMB, nullptr, nullptr, nullptr, offaB, offwB);
            deform_kernel<false><<<dim3(512, 1), 512, 0, stream>>>(
                XH, offaB, offwB, wB, b_cb[0], stI, nullptr, nullptr,
                nullptr, YH);
            conv_offm<true><<<dim3(1024, 1), 512, 0, stream>>>(
                nullptr, nullptr, nullptr, nullptr, nullptr, YH, nullptr,
                wC + 36864, W + OFF_BCOMB + 32, stI, b_bg[0], b_bb[0],
                offaB, offwB);
            deform_kernel<true><<<dim3(512, 1), 512, 0, stream>>>(
                YH, offaB, offwB, wB + 147456, b_cb[1], stI, b_bg[0], b_bb[0],
                BUFB, nullptr);
            float* outb = out + (size_t)Obase[img] * NPIX;
            const float* st1 = stI + 256;
            if (img < 2)
                proj_kernel<false><<<dim3(128, yGrd[img]), 256, 0, stream>>>(
                    BUFB, nullptr, aP + aOffA[img], nullptr,
                    st1, b_bg[1], b_bb[1], lnw, lnb, outb, Ocnt[img], hiSz[img]);
            else
                proj_kernel<true><<<dim3(128, yGrd[img]), 256, 0, stream>>>(
                    BUFB, xin[img], aP + aOffA[img], aP + aOffB[img],
                    st1, b_bg[1], b_bb[1], lnw, lnb, outb, Ocnt[img], hiSz[img]);
        }
    }
}